// Round 4
// baseline (421.394 us; speedup 1.0000x reference)
//
#include <hip/hip_runtime.h>
#include <math.h>

// Problem constants (fixed shapes from setup_inputs)
constexpr int TOPK = 8;
constexpr int NUM_SPECIAL = 999;
constexpr int V = 30522;
constexpr int D = 768;
constexpr int BLOCK = 256;
constexpr int NF4 = 7630;              // float4 count of the 16B-aligned body
constexpr int NK4 = 30;                // strided f4 rounds per thread (bounded)
constexpr int CAP = 512;               // candidate buffer (ties safety)
constexpr int HOTCAP = 64;             // hot-thread list bound

// Monotone map float -> uint32 (order-preserving), packed with ~idx so that
// larger key == (larger value, then SMALLER index) -- matches jax.lax.top_k
// tie-breaking (lower index first among equal values).
__device__ __forceinline__ unsigned long long fkey(float v, unsigned int idx) {
    unsigned int u = __float_as_uint(v);
    u = ((int)u < 0) ? ~u : (u | 0x80000000u);
    return ((unsigned long long)u << 32) | (unsigned long long)(~idx);
}

__device__ __forceinline__ void cmpx(float& a, float& b) {  // desc compare-exchange
    float m = fmaxf(a, b), n = fminf(a, b); a = m; b = n;
}

// Batcher odd-even mergesort, 8 elements, descending (19 CE)
__device__ __forceinline__ void sort8_desc(float (&c)[8]) {
    cmpx(c[0],c[1]); cmpx(c[2],c[3]); cmpx(c[4],c[5]); cmpx(c[6],c[7]);
    cmpx(c[0],c[2]); cmpx(c[1],c[3]); cmpx(c[1],c[2]);
    cmpx(c[4],c[6]); cmpx(c[5],c[7]); cmpx(c[5],c[6]);
    cmpx(c[0],c[4]); cmpx(c[1],c[5]); cmpx(c[2],c[6]); cmpx(c[3],c[7]);
    cmpx(c[2],c[4]); cmpx(c[3],c[5]);
    cmpx(c[1],c[2]); cmpx(c[3],c[4]); cmpx(c[5],c[6]);
}

// R (sorted desc) <- top-8 of R ∪ C (C sorted desc). Half-merge gives a
// bitonic sequence; 3-stage bitonic merge re-sorts it. 8 + 24 VALU.
__device__ __forceinline__ void merge_top8(float (&R)[8], const float (&C)[8]) {
    float m[8];
    #pragma unroll
    for (int j = 0; j < 8; ++j) m[j] = fmaxf(R[j], C[7 - j]);
    cmpx(m[0],m[4]); cmpx(m[1],m[5]); cmpx(m[2],m[6]); cmpx(m[3],m[7]);
    cmpx(m[0],m[2]); cmpx(m[1],m[3]); cmpx(m[4],m[6]); cmpx(m[5],m[7]);
    cmpx(m[0],m[1]); cmpx(m[2],m[3]); cmpx(m[4],m[5]); cmpx(m[6],m[7]);
    #pragma unroll
    for (int j = 0; j < 8; ++j) R[j] = m[j];
}

// branchless sorted-desc top-8 insert (for <=4 straggler elements)
__device__ __forceinline__ void net8(float (&L)[TOPK], float t) {
    #pragma unroll
    for (int j = 0; j < TOPK; ++j) {
        float m = fmaxf(L[j], t); t = fminf(L[j], t); L[j] = m;
    }
}

// Per-wave exact top-8 extraction from 64 sorted-desc 8-lists (pops heads).
__device__ __forceinline__ void wave_extract8(float (&cur)[TOPK], int lane,
                                              float* dst) {
    #pragma unroll
    for (int r = 0; r < TOPK; ++r) {
        float m = cur[0];
        int ml = lane;
        #pragma unroll
        for (int off = 1; off < 64; off <<= 1) {
            float om = __shfl_xor(m, off, 64);
            int   ol = __shfl_xor(ml, off, 64);
            if (om > m || (om == m && ol < ml)) { m = om; ml = ol; }
        }
        if (lane == ml) {
            #pragma unroll
            for (int j = 0; j < TOPK - 1; ++j) cur[j] = cur[j + 1];
            cur[TOPK - 1] = -INFINITY;
        }
        if (lane == 0) dst[r] = m;
    }
}

__global__ __launch_bounds__(BLOCK, 8) void dvat_kernel(
    const float* __restrict__ delta_grad,   // [B,S,D]
    const float* __restrict__ src_embeds,   // [B,S,D]
    const float* __restrict__ emb,          // [V,D]
    const int*   __restrict__ src_tokens,   // [B,S]
    const float* __restrict__ pred_lm,      // [B,S,V]
    const int*   __restrict__ attn,         // [B,S]
    const float* __restrict__ rand_u,       // [B,S]
    int* __restrict__ out)                  // [B,S]
{
    const int pos = blockIdx.x;        // b*S + s
    const int tid = threadIdx.x;
    const int lane = tid & 63;
    const int wave = tid >> 6;

    __shared__ float  sm32[32];                   // 4 waves x sorted top-8
    __shared__ float  s_g8;
    __shared__ int    s_hot[HOTCAP];
    __shared__ int    s_nhot;
    __shared__ int    s_ncand;
    __shared__ unsigned long long sh_cand64[CAP]; // 4 KB
    __shared__ int    s_cand[TOPK];
    __shared__ double s_scores[TOPK];
    __shared__ double s_pd[4], s_ssq[4];
    __shared__ float  shf[2 * D];                 // dg row | se row (6 KB)

    if (tid == 0) { s_nhot = 0; s_ncand = 0; }

    // ---------- early: stage dg/se rows (float4) + prev_dot/src_sq ----------
    // Issued first so these loads land while the big scan runs.
    {
        const float* dg = delta_grad + (size_t)pos * D;
        const float* se = src_embeds + (size_t)pos * D;
        double pd = 0.0, ssq = 0.0;
        if (tid < D / 4) {                        // 192 threads, one float4 each
            float4 g = ((const float4*)dg)[tid];
            float4 e = ((const float4*)se)[tid];
            ((float4*)shf)[tid] = g;
            ((float4*)(shf + D))[tid] = e;
            pd  = (double)g.x * e.x + (double)g.y * e.y
                + (double)g.z * e.z + (double)g.w * e.w;
            ssq = (double)e.x * e.x + (double)e.y * e.y
                + (double)e.z * e.z + (double)e.w * e.w;
        }
        #pragma unroll
        for (int off = 32; off; off >>= 1) {
            pd  += __shfl_down(pd, off, 64);
            ssq += __shfl_down(ssq, off, 64);
        }
        if (lane == 0) { s_pd[wave] = pd; s_ssq[wave] = ssq; }
    }

    // ---------------- Pass 1: chunked sort-merge top-8 scan -----------------
    // Row byte offset = pos*122088; mod 16 is 0 (even pos) or 8 (odd pos).
    // Peel `al` floats so the float4 body is 16B-aligned; thread 0 nets the
    // <=2 prefix/tail stragglers at the end.
    const float* row = pred_lm + (size_t)pos * V;
    const int al = (pos & 1) ? 2 : 0;             // body = elements [al, al+4*NF4)
    const float4* f4 = (const float4*)(row + al);

    float R[8];
    #pragma unroll
    for (int j = 0; j < 8; ++j) R[j] = -INFINITY;

    int ia = tid;
    for (int p = 0; p < 7; ++p, ia += 4 * BLOCK) { // k = 0..27 (all in bounds)
        float4 a = f4[ia];
        float4 b = f4[ia + BLOCK];
        float4 c = f4[ia + 2 * BLOCK];
        float4 d = f4[ia + 3 * BLOCK];
        float ca[8] = {a.x, a.y, a.z, a.w, b.x, b.y, b.z, b.w};
        sort8_desc(ca); merge_top8(R, ca);
        float cb[8] = {c.x, c.y, c.z, c.w, d.x, d.y, d.z, d.w};
        sort8_desc(cb); merge_top8(R, cb);
    }
    {   // k = 28 (full), k = 29 (partial: valid iff idx < NF4)
        float4 a = f4[ia];
        float4 b = {-INFINITY, -INFINITY, -INFINITY, -INFINITY};
        if (ia + BLOCK < NF4) b = f4[ia + BLOCK];
        float ca[8] = {a.x, a.y, a.z, a.w, b.x, b.y, b.z, b.w};
        sort8_desc(ca); merge_top8(R, ca);
    }
    if (tid == 0) {                               // prefix (odd) / tail (even)
        if (al) { net8(R, row[0]);     net8(R, row[1]); }
        else    { net8(R, row[V - 2]); net8(R, row[V - 1]); }
    }
    const float tmax = R[0];                      // thread stream max

    // ---------------- g8 = exact 8th-largest of the row ---------------------
    wave_extract8(R, lane, &sm32[wave * 8]);      // destroys R
    __syncthreads();

    if (wave == 0) {                              // top-8 of the 4x8 survivors
        float c = (lane < 32) ? sm32[lane] : -INFINITY;
        float m = -INFINITY;
        #pragma unroll
        for (int r = 0; r < TOPK; ++r) {
            m = c; int ml = lane;
            #pragma unroll
            for (int off = 1; off < 64; off <<= 1) {
                float om = __shfl_xor(m, off, 64);
                int   ol = __shfl_xor(ml, off, 64);
                if (om > m || (om == m && ol < ml)) { m = om; ml = ol; }
            }
            if (lane == ml) c = -INFINITY;        // pop
        }
        if (lane == 0) s_g8 = m;                  // 8th extracted = exact g8
    }
    __syncthreads();
    const float g8 = s_g8;

    // ---------------- sparse index recovery ---------------------------------
    if (tmax >= g8) {
        int p = atomicAdd(&s_nhot, 1);
        if (p < HOTCAP) s_hot[p] = tid;
    }
    // thread-0 stragglers: checked unconditionally (cover prefix/tail members)
    if (tid == 0) {
        if (al) {
            if (row[0] >= g8) { int p = atomicAdd(&s_ncand, 1); if (p < CAP) sh_cand64[p] = fkey(row[0], 0u); }
            if (row[1] >= g8) { int p = atomicAdd(&s_ncand, 1); if (p < CAP) sh_cand64[p] = fkey(row[1], 1u); }
        } else {
            if (row[V-2] >= g8) { int p = atomicAdd(&s_ncand, 1); if (p < CAP) sh_cand64[p] = fkey(row[V-2], (unsigned)(V-2)); }
            if (row[V-1] >= g8) { int p = atomicAdd(&s_ncand, 1); if (p < CAP) sh_cand64[p] = fkey(row[V-1], (unsigned)(V-1)); }
        }
    }
    __syncthreads();

    if (s_nhot <= HOTCAP) {
        const int nhot = s_nhot;
        const int total = nhot * NK4;
        for (int w = tid; w < total; w += BLOCK) {
            const int h = w / NK4;                // const-div -> magic mul
            const int k = w - h * NK4;
            const int i4 = s_hot[h] + (k << 8);   // stride BLOCK in float4 space
            if (i4 < NF4) {
                float4 f = f4[i4];
                const unsigned base = (unsigned)(al + 4 * i4);
                if (f.x >= g8) { int p = atomicAdd(&s_ncand, 1); if (p < CAP) sh_cand64[p] = fkey(f.x, base); }
                if (f.y >= g8) { int p = atomicAdd(&s_ncand, 1); if (p < CAP) sh_cand64[p] = fkey(f.y, base + 1); }
                if (f.z >= g8) { int p = atomicAdd(&s_ncand, 1); if (p < CAP) sh_cand64[p] = fkey(f.z, base + 2); }
                if (f.w >= g8) { int p = atomicAdd(&s_ncand, 1); if (p < CAP) sh_cand64[p] = fkey(f.w, base + 3); }
            }
        }
    } else {                                      // massive-tie fallback
        for (int i4 = tid; i4 < NF4; i4 += BLOCK) {
            float4 f = f4[i4];
            const unsigned base = (unsigned)(al + 4 * i4);
            if (f.x >= g8) { int p = atomicAdd(&s_ncand, 1); if (p < CAP) sh_cand64[p] = fkey(f.x, base); }
            if (f.y >= g8) { int p = atomicAdd(&s_ncand, 1); if (p < CAP) sh_cand64[p] = fkey(f.y, base + 1); }
            if (f.z >= g8) { int p = atomicAdd(&s_ncand, 1); if (p < CAP) sh_cand64[p] = fkey(f.z, base + 2); }
            if (f.w >= g8) { int p = atomicAdd(&s_ncand, 1); if (p < CAP) sh_cand64[p] = fkey(f.w, base + 3); }
        }
    }
    __syncthreads();
    const int ncand = min(s_ncand, CAP);          // >= 8 by construction

    // ---------------- exact top-8 (value desc, index asc) -------------------
    for (int it = 0; it < TOPK; ++it) {
        if (tid < 64) {
            unsigned long long m = 0ull; int ms = 0;
            for (int j = tid; j < ncand; j += 64) {
                unsigned long long x = sh_cand64[j];
                if (x > m) { m = x; ms = j; }
            }
            #pragma unroll
            for (int off = 32; off; off >>= 1) {
                unsigned long long om = __shfl_down(m, off, 64);
                int os = __shfl_down(ms, off, 64);
                if (om > m) { m = om; ms = os; }
            }
            if (tid == 0) {
                s_cand[it] = (m == 0ull) ? 0 : (int)(~(unsigned int)m);
                sh_cand64[ms] = 0ull;
            }
        }
        __syncthreads();
    }

    // topk_idx *= attention_mask  (mask==0 -> all candidates index 0)
    if (tid == 0 && attn[pos] == 0) {
        #pragma unroll
        for (int k = 0; k < TOPK; ++k) s_cand[k] = 0;
    }
    __syncthreads();

    const double prev_dot = s_pd[0] + s_pd[1] + s_pd[2] + s_pd[3];
    const double src_sq   = s_ssq[0] + s_ssq[1] + s_ssq[2] + s_ssq[3];

    // ---------------- score 8 candidates (2 per wave, fp64) -----------------
    #pragma unroll
    for (int kk = 0; kk < 2; ++kk) {
        const int k = 2 * wave + kk;
        const int v = s_cand[k];
        const float* ev = emb + (size_t)v * D;
        double ddg = 0.0, dse = 0.0, dvv = 0.0;
        for (int ii = lane; ii < D; ii += 64) {
            double e = (double)ev[ii];
            ddg += e * (double)shf[ii];
            dse += e * (double)shf[D + ii];
            dvv += e * e;
        }
        #pragma unroll
        for (int off = 32; off; off >>= 1) {
            ddg += __shfl_down(ddg, off, 64);
            dse += __shfl_down(dse, off, 64);
            dvv += __shfl_down(dvv, off, 64);
        }
        if (lane == 0) {
            double sq = src_sq + dvv - 2.0 * dse;
            if (sq < 0.0) sq = 0.0;
            double dn = sqrt(sq + 1e-20);
            s_scores[k] = (ddg - prev_dot) / dn;   // dir_dot_grad / dir_norm
        }
    }
    __syncthreads();

    // ---------------- filtered argmax + swap blend (thread 0) ---------------
    if (tid == 0) {
        const int src_tok = src_tokens[pos];
        int best = 0;
        double best_s = 0.0;
        bool found = false;
        #pragma unroll
        for (int k = 0; k < TOPK; ++k) {
            const int v = s_cand[k];
            if (v < NUM_SPECIAL || v == src_tok) continue;   // -inf in reference
            const double sc = s_scores[k];
            // jnp.argmax: lowest index wins ties
            if (!found || sc > best_s || (sc == best_s && v < best)) {
                best = v; best_s = sc; found = true;
            }
        }
        const int adv_flip = found ? best : 0;   // argmax of all -inf -> 0
        const bool no_special = (src_tok >= NUM_SPECIAL);
        const bool swap = (rand_u[pos] > 0.7f);  // 1.0 - SWAP_RATIO in f32
        out[pos] = (no_special && swap) ? adv_flip : src_tok;
    }
}

extern "C" void kernel_launch(void* const* d_in, const int* in_sizes, int n_in,
                              void* d_out, int out_size, void* d_ws, size_t ws_size,
                              hipStream_t stream) {
    const float* delta_grad = (const float*)d_in[0];
    const float* src_embeds = (const float*)d_in[1];
    const float* emb        = (const float*)d_in[2];
    const int*   src_tokens = (const int*)d_in[3];
    const float* pred_lm    = (const float*)d_in[4];
    const int*   attn       = (const int*)d_in[5];
    const float* randu      = (const float*)d_in[6];
    int* out = (int*)d_out;

    const int BS = in_sizes[3];   // B*S = 2048 positions
    dvat_kernel<<<BS, BLOCK, 0, stream>>>(delta_grad, src_embeds, emb,
                                          src_tokens, pred_lm, attn, randu, out);
}